// Round 1
// baseline (318.914 us; speedup 1.0000x reference)
//
#include <hip/hip_runtime.h>
#include <hip/hip_bf16.h>
#include <stdint.h>

typedef __attribute__((ext_vector_type(8))) short short8;
typedef __attribute__((ext_vector_type(4))) float f32x4;

#define T_DIM 256
#define NBATCH 64

__device__ __forceinline__ void gload_lds16(const void* g, void* l) {
    __builtin_amdgcn_global_load_lds(
        (const __attribute__((address_space(1))) void*)g,
        (__attribute__((address_space(3))) void*)l, 16, 0, 0);
}

// ---------------- prep: W [(K+1)][O] fp32 -> WT_hi/WT_lo [O][K] bf16 + bias[O] ----
__global__ void prep_w(const float* __restrict__ W, __hip_bfloat16* __restrict__ WTh,
                       __hip_bfloat16* __restrict__ WTl, float* __restrict__ bias,
                       int K, int O) {
    int idx = blockIdx.x * blockDim.x + threadIdx.x;
    int total = O * K;
    if (idx < total) {
        int o = idx / K, i = idx % K;
        float w = W[(size_t)i * O + o];
        __hip_bfloat16 h = __float2bfloat16(w);
        WTh[idx] = h;
        WTl[idx] = __float2bfloat16(w - __bfloat162float(h));
    }
    if (idx < O) bias[idx] = W[(size_t)K * O + idx];
}

// ---------------- prep: x [64][512][256] fp32 -> xh/xl [64][256][512] bf16 --------
__global__ void prep_x(const float* __restrict__ x, __hip_bfloat16* __restrict__ xh,
                       __hip_bfloat16* __restrict__ xl) {
    __shared__ float tile[32][33];
    int b = blockIdx.z;
    int i0 = blockIdx.x * 32;   // input-dim 512
    int t0 = blockIdx.y * 32;   // time 256
    int tx = threadIdx.x;       // 0..31
    int ty = threadIdx.y;       // 0..7
    for (int dy = 0; dy < 32; dy += 8)
        tile[ty + dy][tx] = x[((size_t)b * 512 + i0 + ty + dy) * T_DIM + t0 + tx];
    __syncthreads();
    for (int dy = 0; dy < 32; dy += 8) {
        float w = tile[tx][ty + dy];
        size_t dst = ((size_t)b * T_DIM + t0 + ty + dy) * 512 + i0 + tx;
        __hip_bfloat16 h = __float2bfloat16(w);
        xh[dst] = h;
        xl[dst] = __float2bfloat16(w - __bfloat162float(h));
    }
}

// ---------------- batched multi-pass GEMM: pre[b][o][t] = sum_p A_p[o][:]·B_p[b][t][:] + bias[o]
// A planes: bf16 [O][K]; B planes: bf16 [NBATCH][T_DIM][K]; tile 128x128, BK=64
__global__ __launch_bounds__(256) void gemm_mfma(
    const __hip_bfloat16* __restrict__ A0, const __hip_bfloat16* __restrict__ A1,
    const __hip_bfloat16* __restrict__ A2,
    const __hip_bfloat16* __restrict__ B0, const __hip_bfloat16* __restrict__ B1,
    const __hip_bfloat16* __restrict__ B2,
    const float* __restrict__ bias, float* __restrict__ Cout,
    int O, int K, int npass) {
    __shared__ __hip_bfloat16 As[128 * 64];
    __shared__ __hip_bfloat16 Bs[128 * 64];
    const int b = blockIdx.z;
    const int o0 = blockIdx.x * 128;
    const int t0 = blockIdx.y * 128;
    const int tid = threadIdx.x;
    const int lane = tid & 63;
    const int wave = tid >> 6;
    const int wm = wave >> 1, wn = wave & 1;

    const __hip_bfloat16* Ap[3] = {A0, A1, A2};
    const __hip_bfloat16* Bp[3] = {B0, B1, B2};

    f32x4 acc[4][4] = {};

    const int srow = tid >> 3;         // 0..31 (row within 32-row stage chunk)
    const int skb  = (tid & 7) * 16;   // linear dest byte within 128B row

    for (int p = 0; p < npass; ++p) {
        const __hip_bfloat16* Aptr = Ap[p];
        const __hip_bfloat16* Bptr = Bp[p] + (size_t)b * T_DIM * K;
        for (int k0 = 0; k0 < K; k0 += 64) {
            // stage A[o0..o0+127][k0..k0+63], B[t0..t0+127][k0..k0+63]
            // LDS[row][kb] = G[row][kb ^ ((row&7)<<4)]  (pre-swizzled source, linear dest)
#pragma unroll
            for (int r = 0; r < 4; ++r) {
                int row = srow + r * 32;
                int src_kb = skb ^ ((row & 7) << 4);
                const char* gA = (const char*)(Aptr + (size_t)(o0 + row) * K + k0) + src_kb;
                gload_lds16(gA, (char*)As + row * 128 + skb);
                const char* gB = (const char*)(Bptr + (size_t)(t0 + row) * K + k0) + src_kb;
                gload_lds16(gB, (char*)Bs + row * 128 + skb);
            }
            __syncthreads();
#pragma unroll
            for (int kk = 0; kk < 2; ++kk) {
                short8 af[4], bfr[4];
#pragma unroll
                for (int i = 0; i < 4; ++i) {
                    int row = wm * 64 + i * 16 + (lane & 15);
                    int kb = (((lane >> 4) * 8) + kk * 32) * 2;
                    kb ^= (row & 7) << 4;
                    af[i] = *(const short8*)((const char*)As + row * 128 + kb);
                }
#pragma unroll
                for (int j = 0; j < 4; ++j) {
                    int row = wn * 64 + j * 16 + (lane & 15);
                    int kb = (((lane >> 4) * 8) + kk * 32) * 2;
                    kb ^= (row & 7) << 4;
                    bfr[j] = *(const short8*)((const char*)Bs + row * 128 + kb);
                }
#pragma unroll
                for (int i = 0; i < 4; ++i)
#pragma unroll
                    for (int j = 0; j < 4; ++j)
                        acc[i][j] = __builtin_amdgcn_mfma_f32_16x16x32_bf16(
                            af[i], bfr[j], acc[i][j], 0, 0, 0);
            }
            __syncthreads();
        }
    }
    // epilogue: D col(t)=lane&15, row(o)=(lane>>4)*4+r   [m89 layout]
#pragma unroll
    for (int i = 0; i < 4; ++i) {
        int ob = o0 + wm * 64 + i * 16 + ((lane >> 4) * 4);
#pragma unroll
        for (int j = 0; j < 4; ++j) {
            int t = t0 + wn * 64 + j * 16 + (lane & 15);
            float* dst = Cout + ((size_t)b * O + ob) * T_DIM + t;
#pragma unroll
            for (int r = 0; r < 4; ++r)
                dst[(size_t)r * T_DIM] = acc[i][j][r] + bias[ob + r];
        }
    }
}

// ---------------- LIF scan: hidden layers (emit bf16 spikes, transposed [b][t][o])
__global__ void lif_hidden(const float* __restrict__ pre, __hip_bfloat16* __restrict__ st,
                           const float* __restrict__ beta_p, const float* __restrict__ thr_p,
                           int O) {
    int idx = blockIdx.x * blockDim.x + threadIdx.x;  // b*O + o
    int b = idx / O, o = idx - b * O;
    float sb = 1.f / (1.f + expf(-beta_p[0]));
    float thr = thr_p[0];
    float mem = 0.f;
    const float* src = pre + (size_t)idx * T_DIM;
    __hip_bfloat16* dst = st + (size_t)b * T_DIM * O + o;
    for (int t = 0; t < T_DIM; ++t) {
        float mu = __fadd_rn(__fmul_rn(sb, mem), src[t]);
        float spike = (mu >= thr) ? 1.f : 0.f;
        mem = mu - spike * thr;
        dst[(size_t)t * O] = __float2bfloat16(spike);
    }
}

// ---------------- LIF scan: final layer (spikes + mems fp32, [b][o][t]) ----------
__global__ void lif_final(const float* __restrict__ pre, float* __restrict__ osp,
                          float* __restrict__ omem, const float* __restrict__ beta_p,
                          const float* __restrict__ thr_p) {
    int idx = blockIdx.x * blockDim.x + threadIdx.x;  // b*256 + o  (16384 total)
    float sb = 1.f / (1.f + expf(-beta_p[0]));
    float thr = thr_p[0];
    float mem = 0.f;
    const float* src = pre + (size_t)idx * T_DIM;
    float* ds = osp + (size_t)idx * T_DIM;
    float* dm = omem + (size_t)idx * T_DIM;
    for (int t = 0; t < T_DIM; ++t) {
        dm[t] = mem;  // mem entering this timestep
        float mu = __fadd_rn(__fmul_rn(sb, mem), src[t]);
        float spike = (mu >= thr) ? 1.f : 0.f;
        ds[t] = spike;
        mem = mu - spike * thr;
    }
}

extern "C" void kernel_launch(void* const* d_in, const int* in_sizes, int n_in,
                              void* d_out, int out_size, void* d_ws, size_t ws_size,
                              hipStream_t stream) {
    const float* x  = (const float*)d_in[0];
    const float* W0 = (const float*)d_in[1];
    const float* W1 = (const float*)d_in[2];
    const float* W2 = (const float*)d_in[3];
    const float* beta = (const float*)d_in[4];
    const float* thr  = (const float*)d_in[5];
    float* out = (float*)d_out;

    char* ws = (char*)d_ws;
    size_t off = 0;
    auto alloc = [&](size_t bytes) {
        size_t r = off;
        off = (off + bytes + 255) & ~(size_t)255;
        return r;
    };
    __hip_bfloat16* w0h = (__hip_bfloat16*)(ws + alloc(1024 * 512 * 2));
    __hip_bfloat16* w0l = (__hip_bfloat16*)(ws + alloc(1024 * 512 * 2));
    float* b0 = (float*)(ws + alloc(1024 * 4));
    __hip_bfloat16* w1h = (__hip_bfloat16*)(ws + alloc(1024 * 1024 * 2));
    __hip_bfloat16* w1l = (__hip_bfloat16*)(ws + alloc(1024 * 1024 * 2));
    float* b1 = (float*)(ws + alloc(1024 * 4));
    __hip_bfloat16* w2h = (__hip_bfloat16*)(ws + alloc(256 * 1024 * 2));
    __hip_bfloat16* w2l = (__hip_bfloat16*)(ws + alloc(256 * 1024 * 2));
    float* b2 = (float*)(ws + alloc(256 * 4));
    __hip_bfloat16* xh = (__hip_bfloat16*)(ws + alloc((size_t)NBATCH * T_DIM * 512 * 2));
    __hip_bfloat16* xl = (__hip_bfloat16*)(ws + alloc((size_t)NBATCH * T_DIM * 512 * 2));
    __hip_bfloat16* S  = (__hip_bfloat16*)(ws + alloc((size_t)NBATCH * T_DIM * 1024 * 2));
    float* pre = (float*)(ws + alloc((size_t)NBATCH * 1024 * T_DIM * 4));
    (void)ws_size; (void)in_sizes; (void)n_in; (void)out_size;

    // prep weights
    prep_w<<<(1024 * 512 + 255) / 256, 256, 0, stream>>>(W0, w0h, w0l, b0, 512, 1024);
    prep_w<<<(1024 * 1024 + 255) / 256, 256, 0, stream>>>(W1, w1h, w1l, b1, 1024, 1024);
    prep_w<<<(256 * 1024 + 255) / 256, 256, 0, stream>>>(W2, w2h, w2l, b2, 1024, 256);
    // prep x (transpose + split)
    prep_x<<<dim3(16, 8, 64), dim3(32, 8), 0, stream>>>(x, xh, xl);

    // Layer 1: O=1024, K=512, 3 passes: xh*Wh + xl*Wh + xh*Wl
    gemm_mfma<<<dim3(8, 2, 64), 256, 0, stream>>>(w0h, w0h, w0l, xh, xl, xh,
                                                  b0, pre, 1024, 512, 3);
    lif_hidden<<<(NBATCH * 1024) / 256, 256, 0, stream>>>(pre, S, beta, thr, 1024);

    // Layer 2: O=1024, K=1024, 2 passes: S*Wh + S*Wl
    gemm_mfma<<<dim3(8, 2, 64), 256, 0, stream>>>(w1h, w1l, w1l, S, S, S,
                                                  b1, pre, 1024, 1024, 2);
    lif_hidden<<<(NBATCH * 1024) / 256, 256, 0, stream>>>(pre, S, beta, thr, 1024);

    // Layer 3: O=256, K=1024, 2 passes
    gemm_mfma<<<dim3(2, 2, 64), 256, 0, stream>>>(w2h, w2l, w2l, S, S, S,
                                                  b2, pre, 256, 1024, 2);
    lif_final<<<(NBATCH * 256) / 256, 256, 0, stream>>>(pre, out, out + (size_t)NBATCH * 256 * T_DIM,
                                                        beta, thr);
}

// Round 2
// 296.035 us; speedup vs baseline: 1.0773x; 1.0773x over previous
//
#include <hip/hip_runtime.h>
#include <hip/hip_bf16.h>
#include <stdint.h>

typedef __attribute__((ext_vector_type(8))) short short8;
typedef __attribute__((ext_vector_type(4))) float f32x4;

#define T_DIM 256
#define NBATCH 64

__device__ __forceinline__ void gload_lds16(const void* g, void* l) {
    __builtin_amdgcn_global_load_lds(
        (const __attribute__((address_space(1))) void*)g,
        (__attribute__((address_space(3))) void*)l, 16, 0, 0);
}

// ---------------- prep: W [(K+1)][O] fp32 -> WT_hi/WT_lo [O][K] bf16 + bias[O] ----
__global__ void prep_w(const float* __restrict__ W, __hip_bfloat16* __restrict__ WTh,
                       __hip_bfloat16* __restrict__ WTl, float* __restrict__ bias,
                       int K, int O) {
    int idx = blockIdx.x * blockDim.x + threadIdx.x;
    int total = O * K;
    if (idx < total) {
        int o = idx / K, i = idx % K;
        float w = W[(size_t)i * O + o];
        __hip_bfloat16 h = __float2bfloat16(w);
        WTh[idx] = h;
        WTl[idx] = __float2bfloat16(w - __bfloat162float(h));
    }
    if (idx < O) bias[idx] = W[(size_t)K * O + idx];
}

// ---------------- prep: x [64][512][256] fp32 -> xh/xl [64][256][512] bf16 --------
__global__ void prep_x(const float* __restrict__ x, __hip_bfloat16* __restrict__ xh,
                       __hip_bfloat16* __restrict__ xl) {
    __shared__ float tile[32][33];
    int b = blockIdx.z;
    int i0 = blockIdx.x * 32;   // input-dim 512
    int t0 = blockIdx.y * 32;   // time 256
    int tx = threadIdx.x;       // 0..31
    int ty = threadIdx.y;       // 0..7
    for (int dy = 0; dy < 32; dy += 8)
        tile[ty + dy][tx] = x[((size_t)b * 512 + i0 + ty + dy) * T_DIM + t0 + tx];
    __syncthreads();
    for (int dy = 0; dy < 32; dy += 8) {
        float w = tile[tx][ty + dy];
        size_t dst = ((size_t)b * T_DIM + t0 + ty + dy) * 512 + i0 + tx;
        __hip_bfloat16 h = __float2bfloat16(w);
        xh[dst] = h;
        xl[dst] = __float2bfloat16(w - __bfloat162float(h));
    }
}

// ---------------- batched multi-pass GEMM ----------------------------------------
// pre[b][t][o] = sum_p A_p[o][:]·B_p[b][t][:] + bias[o]   (C TRANSPOSED layout)
// A planes: bf16 [O][K]; B planes: bf16 [NBATCH][T_DIM][K]; tile 128x128, BK=64
// 1D grid, XCD-aware mapping: xcd = bid&7 owns batches [xcd*8, xcd*8+8),
// processes each batch's (nOx*nTy) tiles contiguously -> B-tile + weights hot in
// that XCD's private L2.
__global__ __launch_bounds__(256) void gemm_mfma(
    const __hip_bfloat16* __restrict__ A0, const __hip_bfloat16* __restrict__ A1,
    const __hip_bfloat16* __restrict__ A2,
    const __hip_bfloat16* __restrict__ B0, const __hip_bfloat16* __restrict__ B1,
    const __hip_bfloat16* __restrict__ B2,
    const float* __restrict__ bias, float* __restrict__ Cout,
    int O, int K, int npass, int nOx, int nTy) {
    __shared__ __hip_bfloat16 As[128 * 64];
    __shared__ __hip_bfloat16 Bs[128 * 64];

    // XCD-aware decomposition (grid = 64 * nOx * nTy, batches_per_xcd = 8)
    const int fid = blockIdx.x;
    const int bpb = nOx * nTy;            // blocks per batch
    const int xcd = fid & 7;
    const int k_in = fid >> 3;            // 0 .. 8*bpb-1
    const int b = xcd * 8 + k_in / bpb;
    const int r_in = k_in % bpb;
    const int o0 = (r_in / nTy) * 128;
    const int t0 = (r_in % nTy) * 128;

    const int tid = threadIdx.x;
    const int lane = tid & 63;
    const int wave = tid >> 6;
    const int wm = wave >> 1, wn = wave & 1;

    const __hip_bfloat16* Ap[3] = {A0, A1, A2};
    const __hip_bfloat16* Bp[3] = {B0, B1, B2};

    f32x4 acc[4][4] = {};

    const int srow = tid >> 3;         // 0..31 (row within 32-row stage chunk)
    const int skb  = (tid & 7) * 16;   // linear dest byte within 128B row

    for (int p = 0; p < npass; ++p) {
        const __hip_bfloat16* Aptr = Ap[p];
        const __hip_bfloat16* Bptr = Bp[p] + (size_t)b * T_DIM * K;
        for (int k0 = 0; k0 < K; k0 += 64) {
            // stage A[o0..o0+127][k0..k0+63], B[t0..t0+127][k0..k0+63]
            // LDS[row][kb] = G[row][kb ^ ((row&7)<<4)]  (pre-swizzled source, linear dest)
#pragma unroll
            for (int r = 0; r < 4; ++r) {
                int row = srow + r * 32;
                int src_kb = skb ^ ((row & 7) << 4);
                const char* gA = (const char*)(Aptr + (size_t)(o0 + row) * K + k0) + src_kb;
                gload_lds16(gA, (char*)As + row * 128 + skb);
                const char* gB = (const char*)(Bptr + (size_t)(t0 + row) * K + k0) + src_kb;
                gload_lds16(gB, (char*)Bs + row * 128 + skb);
            }
            __syncthreads();
#pragma unroll
            for (int kk = 0; kk < 2; ++kk) {
                short8 af[4], bfr[4];
#pragma unroll
                for (int i = 0; i < 4; ++i) {
                    int row = wm * 64 + i * 16 + (lane & 15);
                    int kb = (((lane >> 4) * 8) + kk * 32) * 2;
                    kb ^= (row & 7) << 4;
                    af[i] = *(const short8*)((const char*)As + row * 128 + kb);
                }
#pragma unroll
                for (int j = 0; j < 4; ++j) {
                    int row = wn * 64 + j * 16 + (lane & 15);
                    int kb = (((lane >> 4) * 8) + kk * 32) * 2;
                    kb ^= (row & 7) << 4;
                    bfr[j] = *(const short8*)((const char*)Bs + row * 128 + kb);
                }
#pragma unroll
                for (int i = 0; i < 4; ++i)
#pragma unroll
                    for (int j = 0; j < 4; ++j)
                        acc[i][j] = __builtin_amdgcn_mfma_f32_16x16x32_bf16(
                            af[i], bfr[j], acc[i][j], 0, 0, 0);
            }
            __syncthreads();
        }
    }
    // epilogue: D col(t)=lane&15, row(o)=(lane>>4)*4+r   [m89 layout]
    // C layout [b][t][o]: the 4 r's are contiguous floats -> one float4 store/lane
#pragma unroll
    for (int i = 0; i < 4; ++i) {
        int ob = o0 + wm * 64 + i * 16 + ((lane >> 4) * 4);
        f32x4 bv = *(const f32x4*)(bias + ob);
#pragma unroll
        for (int j = 0; j < 4; ++j) {
            int t = t0 + wn * 64 + j * 16 + (lane & 15);
            f32x4 v = acc[i][j] + bv;
            *(f32x4*)(Cout + ((size_t)b * T_DIM + t) * O + ob) = v;
        }
    }
}

// ---------------- LIF scan: hidden layers -----------------------------------------
// pre [b][t][o] fp32 -> spikes S [b][t][o] bf16.  Thread = (b,o); reads/writes
// coalesced across the wave at every t step.
__global__ void lif_hidden(const float* __restrict__ pre, __hip_bfloat16* __restrict__ st,
                           const float* __restrict__ beta_p, const float* __restrict__ thr_p,
                           int O) {
    int idx = blockIdx.x * blockDim.x + threadIdx.x;  // b*O + o
    int b = idx / O, o = idx - b * O;
    float sb = 1.f / (1.f + expf(-beta_p[0]));
    float thr = thr_p[0];
    float mem = 0.f;
    const float* src = pre + (size_t)b * T_DIM * O + o;
    __hip_bfloat16* dst = st + (size_t)b * T_DIM * O + o;
    for (int t = 0; t < T_DIM; ++t) {
        float mu = __fadd_rn(__fmul_rn(sb, mem), src[(size_t)t * O]);
        float spike = (mu >= thr) ? 1.f : 0.f;
        mem = mu - spike * thr;
        dst[(size_t)t * O] = __float2bfloat16(spike);
    }
}

// ---------------- LIF scan: final layer -------------------------------------------
// pre [b][t][256] fp32 -> out spikes [b][256][t], mems [b][256][t] fp32
__global__ void lif_final(const float* __restrict__ pre, float* __restrict__ osp,
                          float* __restrict__ omem, const float* __restrict__ beta_p,
                          const float* __restrict__ thr_p) {
    int idx = blockIdx.x * blockDim.x + threadIdx.x;  // b*256 + o  (16384 total)
    int b = idx >> 8, o = idx & 255;
    float sb = 1.f / (1.f + expf(-beta_p[0]));
    float thr = thr_p[0];
    float mem = 0.f;
    const float* src = pre + (size_t)b * T_DIM * 256 + o;
    float* ds = osp + (size_t)idx * T_DIM;
    float* dm = omem + (size_t)idx * T_DIM;
    for (int t = 0; t < T_DIM; ++t) {
        dm[t] = mem;  // mem entering this timestep
        float mu = __fadd_rn(__fmul_rn(sb, mem), src[(size_t)t * 256]);
        float spike = (mu >= thr) ? 1.f : 0.f;
        ds[t] = spike;
        mem = mu - spike * thr;
    }
}

extern "C" void kernel_launch(void* const* d_in, const int* in_sizes, int n_in,
                              void* d_out, int out_size, void* d_ws, size_t ws_size,
                              hipStream_t stream) {
    const float* x  = (const float*)d_in[0];
    const float* W0 = (const float*)d_in[1];
    const float* W1 = (const float*)d_in[2];
    const float* W2 = (const float*)d_in[3];
    const float* beta = (const float*)d_in[4];
    const float* thr  = (const float*)d_in[5];
    float* out = (float*)d_out;

    char* ws = (char*)d_ws;
    size_t off = 0;
    auto alloc = [&](size_t bytes) {
        size_t r = off;
        off = (off + bytes + 255) & ~(size_t)255;
        return r;
    };
    __hip_bfloat16* w0h = (__hip_bfloat16*)(ws + alloc(1024 * 512 * 2));
    __hip_bfloat16* w0l = (__hip_bfloat16*)(ws + alloc(1024 * 512 * 2));
    float* b0 = (float*)(ws + alloc(1024 * 4));
    __hip_bfloat16* w1h = (__hip_bfloat16*)(ws + alloc(1024 * 1024 * 2));
    __hip_bfloat16* w1l = (__hip_bfloat16*)(ws + alloc(1024 * 1024 * 2));
    float* b1 = (float*)(ws + alloc(1024 * 4));
    __hip_bfloat16* w2h = (__hip_bfloat16*)(ws + alloc(256 * 1024 * 2));
    __hip_bfloat16* w2l = (__hip_bfloat16*)(ws + alloc(256 * 1024 * 2));
    float* b2 = (float*)(ws + alloc(256 * 4));
    __hip_bfloat16* xh = (__hip_bfloat16*)(ws + alloc((size_t)NBATCH * T_DIM * 512 * 2));
    __hip_bfloat16* xl = (__hip_bfloat16*)(ws + alloc((size_t)NBATCH * T_DIM * 512 * 2));
    __hip_bfloat16* S  = (__hip_bfloat16*)(ws + alloc((size_t)NBATCH * T_DIM * 1024 * 2));
    float* pre = (float*)(ws + alloc((size_t)NBATCH * 1024 * T_DIM * 4));
    (void)ws_size; (void)in_sizes; (void)n_in; (void)out_size;

    // prep weights
    prep_w<<<(1024 * 512 + 255) / 256, 256, 0, stream>>>(W0, w0h, w0l, b0, 512, 1024);
    prep_w<<<(1024 * 1024 + 255) / 256, 256, 0, stream>>>(W1, w1h, w1l, b1, 1024, 1024);
    prep_w<<<(256 * 1024 + 255) / 256, 256, 0, stream>>>(W2, w2h, w2l, b2, 1024, 256);
    // prep x (transpose + split)
    prep_x<<<dim3(16, 8, 64), dim3(32, 8), 0, stream>>>(x, xh, xl);

    // Layer 1: O=1024, K=512, 3 passes: xh*Wh + xl*Wh + xh*Wl   (grid = 64*16)
    gemm_mfma<<<dim3(1024), 256, 0, stream>>>(w0h, w0h, w0l, xh, xl, xh,
                                              b0, pre, 1024, 512, 3, 8, 2);
    lif_hidden<<<(NBATCH * 1024) / 256, 256, 0, stream>>>(pre, S, beta, thr, 1024);

    // Layer 2: O=1024, K=1024, 2 passes: S*Wh + S*Wl
    gemm_mfma<<<dim3(1024), 256, 0, stream>>>(w1h, w1l, w1l, S, S, S,
                                              b1, pre, 1024, 1024, 2, 8, 2);
    lif_hidden<<<(NBATCH * 1024) / 256, 256, 0, stream>>>(pre, S, beta, thr, 1024);

    // Layer 3: O=256, K=1024, 2 passes   (grid = 64*4)
    gemm_mfma<<<dim3(256), 256, 0, stream>>>(w2h, w2l, w2l, S, S, S,
                                             b2, pre, 256, 1024, 2, 2, 2);
    lif_final<<<(NBATCH * 256) / 256, 256, 0, stream>>>(pre, out, out + (size_t)NBATCH * 256 * T_DIM,
                                                        beta, thr);
}